// Round 24
// baseline (122.694 us; speedup 1.0000x reference)
//
#include <hip/hip_runtime.h>
#include <hip/hip_bf16.h>

// B=2, T=2048, C=1024, H=16, D=64
// convx -> convt(W_attn) -> qkv_gemm (128x192, 2 blocks/CU, 8mx8n XCD chunks)
// -> attn_v17 (two q-tiles per warp, dual-chain ILP, 128-row groups) ->
// convt -> proj_gemm

typedef __attribute__((ext_vector_type(8))) short bf16x8;
typedef __attribute__((ext_vector_type(4))) short bf16x4;
typedef __attribute__((ext_vector_type(4))) float f32x4;

__device__ __forceinline__ short f2bs(float f) {
    union { __hip_bfloat16 h; short s; } u;
    u.h = __float2bfloat16(f);
    return u.s;
}

__device__ __forceinline__ short f2bs_trunc(float f) {
    return (short)(__float_as_uint(f) >> 16);
}

#define GLOAD_LDS16(gp, lp)                                                        \
    __builtin_amdgcn_global_load_lds((const __attribute__((address_space(1))) void*)(gp), \
                                     (__attribute__((address_space(3))) void*)(lp), 16, 0, 0)

// ---------------------------------------------------------------------------
__global__ __launch_bounds__(256) void convx(
    const float* __restrict__ X, short* __restrict__ Xb)
{
    const size_t i = ((size_t)blockIdx.x * 256 + threadIdx.x) * 8;
    float4 a = *(const float4*)(X + i);
    float4 b = *(const float4*)(X + i + 4);
    bf16x8 s;
    s[0] = f2bs(a.x); s[1] = f2bs(a.y); s[2] = f2bs(a.z); s[3] = f2bs(a.w);
    s[4] = f2bs(b.x); s[5] = f2bs(b.y); s[6] = f2bs(b.z); s[7] = f2bs(b.w);
    *(bf16x8*)(Xb + i) = s;
}

// ---------------------------------------------------------------------------
__global__ __launch_bounds__(256) void convt(
    const float* __restrict__ W, short* __restrict__ Wt, int K, int N)
{
    __shared__ short t[64 * 72];
    const int tid = threadIdx.x;
    const int n0 = blockIdx.x * 64, k0 = blockIdx.y * 64;
    #pragma unroll
    for (int i = 0; i < 4; i++) {
        int k = (tid >> 4) + i * 16;
        int n = (tid & 15) * 4;
        float4 v = *(const float4*)(W + (size_t)(k0 + k) * N + n0 + n);
        t[(n + 0) * 72 + k] = f2bs(v.x);
        t[(n + 1) * 72 + k] = f2bs(v.y);
        t[(n + 2) * 72 + k] = f2bs(v.z);
        t[(n + 3) * 72 + k] = f2bs(v.w);
    }
    __syncthreads();
    #pragma unroll
    for (int i = 0; i < 2; i++) {
        int n  = (tid >> 3) + i * 32;
        int kc = (tid & 7) * 8;
        bf16x8 v = *(const bf16x8*)&t[n * 72 + kc];
        *(bf16x8*)(Wt + (size_t)(n0 + n) * K + k0 + kc) = v;
    }
}

// ---------------------------------------------------------------------------
// Kernel 1: QKV GEMM, 128x192 tile, BK=64, 8 waves, 2 blocks/CU, vmcnt(5),
// 8m x 8n XCD chunks. V via LDS-transpose epilogue.
// ---------------------------------------------------------------------------
__global__ __launch_bounds__(512) void qkv_gemm(
    const short* __restrict__ Xb, const short* __restrict__ Wt,
    const float* __restrict__ bias,
    short* __restrict__ Qw, short* __restrict__ Kw, short* __restrict__ Vt)
{
    __shared__ short LB[40960];           // A dbuf 2x8192, B dbuf 2x12288

    const int tid  = threadIdx.x;
    const int lane = tid & 63;
    const int wid  = tid >> 6;
    const int wm = wid >> 2, wn = wid & 3;
    const int g = lane >> 4, cc = lane & 15;
    const int sw = cc & 7;

    const int bid   = blockIdx.x;
    const int xcd   = bid & 7;
    const int r     = bid >> 3;
    const int m0 = ((xcd & 3) * 8 + (r & 7)) * 128;
    const int n0 = ((xcd >> 2) * 8 + (r >> 3)) * 192;

    f32x4 acc[4][3];
    const f32x4 z4 = {0.f, 0.f, 0.f, 0.f};
    #pragma unroll
    for (int i = 0; i < 4; i++)
        #pragma unroll
        for (int j = 0; j < 3; j++) acc[i][j] = z4;

    auto STAGE = [&](int t, int buf) {
        const int k0 = t * 64;
        short* Ab = LB + buf * 8192;
        short* Bb = LB + 16384 + buf * 12288;
        #pragma unroll
        for (int j = 0; j < 2; j++) {
            int c = j * 512 + tid;
            int row = c >> 3, sch = (c & 7) ^ (row & 7);
            GLOAD_LDS16(Xb + (size_t)(m0 + row) * 1024 + k0 + sch * 8, Ab + c * 8);
        }
        #pragma unroll
        for (int j = 0; j < 3; j++) {
            int c = j * 512 + tid;
            int row = c >> 3, sch = (c & 7) ^ (row & 7);
            GLOAD_LDS16(Wt + (size_t)(n0 + row) * 1024 + k0 + sch * 8, Bb + c * 8);
        }
    };

    STAGE(0, 0);
    STAGE(1, 1);
    asm volatile("s_waitcnt vmcnt(5)" ::: "memory");
    asm volatile("s_barrier" ::: "memory");

    const int NT = 16;
    for (int t = 0; t < NT; t++) {
        const short* Ab = LB + (t & 1) * 8192;
        const short* Bb = LB + 16384 + (t & 1) * 12288;

        bf16x8 bfr[3][2];
        #pragma unroll
        for (int nf = 0; nf < 3; nf++)
            #pragma unroll
            for (int kk = 0; kk < 2; kk++)
                bfr[nf][kk] = *(const bf16x8*)&Bb[(wn * 48 + nf * 16 + cc) * 64 +
                                                  ((kk * 4 + g) ^ sw) * 8];
        bf16x8 af[4][2];
        #pragma unroll
        for (int mf = 0; mf < 4; mf++)
            #pragma unroll
            for (int kk = 0; kk < 2; kk++)
                af[mf][kk] = *(const bf16x8*)&Ab[(wm * 64 + mf * 16 + cc) * 64 +
                                                 ((kk * 4 + g) ^ sw) * 8];
        __builtin_amdgcn_s_setprio(1);
        #pragma unroll
        for (int mf = 0; mf < 4; mf++)
            #pragma unroll
            for (int nf = 0; nf < 3; nf++)
                #pragma unroll
                for (int kk = 0; kk < 2; kk++)
                    acc[mf][nf] = __builtin_amdgcn_mfma_f32_16x16x32_bf16(
                        af[mf][kk], bfr[nf][kk], acc[mf][nf], 0, 0, 0);
        __builtin_amdgcn_s_setprio(0);

        asm volatile("s_barrier" ::: "memory");
        if (t + 2 < NT) {
            STAGE(t + 2, t & 1);
            asm volatile("s_waitcnt vmcnt(5)" ::: "memory");
            asm volatile("s_barrier" ::: "memory");
        } else if (t + 1 < NT) {
            asm volatile("s_waitcnt vmcnt(0)" ::: "memory");
            asm volatile("s_barrier" ::: "memory");
        }
    }

    // ---- epilogue ----
    const float QSCALE = 0.04508422976f;
    const int vs = (n0 > 2048) ? n0 : 2048;
    const int nV = n0 + 192 - vs;
    short* Vstage = LB;                              // overlay [vcol][136]

    __syncthreads();

    #pragma unroll
    for (int nf = 0; nf < 3; nf++) {
        int col = n0 + wn * 48 + nf * 16 + cc;
        int which = col >> 10;
        int ci = col & 1023;
        int h = ci >> 6, d = ci & 63;
        float bv = bias[col];
        #pragma unroll
        for (int mf = 0; mf < 4; mf++) {
            if (which == 2) {
                int tl = wm * 64 + mf * 16 + g * 4;
                int pl = (tl & ~31) | (((tl >> 2) & 3) * 8 + ((tl >> 4) & 1) * 4);
                bf16x4 pk;
                #pragma unroll
                for (int r2 = 0; r2 < 4; r2++) pk[r2] = f2bs(acc[mf][nf][r2] + bv);
                *(bf16x4*)&Vstage[(col - vs) * 136 + pl] = pk;
            } else {
                #pragma unroll
                for (int r2 = 0; r2 < 4; r2++) {
                    int row = m0 + wm * 64 + mf * 16 + g * 4 + r2;
                    int b = row >> 11, tt = row & 2047;
                    int bh = b * 16 + h;
                    float v = acc[mf][nf][r2] + bv;
                    if (which == 0) Qw[((size_t)bh * 2048 + tt) * 64 + d] = f2bs(v * QSCALE);
                    else            Kw[((size_t)bh * 2048 + tt) * 64 + d] = f2bs(v);
                }
            }
        }
    }

    if (nV > 0) {
        __syncthreads();
        const int bb = m0 >> 11;
        const int tbase = m0 & 2047;
        const int total = nV * 16;
        for (int cidx = tid; cidx < total; cidx += 512) {
            int vc = cidx >> 4, toff = (cidx & 15) * 8;
            bf16x8 v = *(const bf16x8*)&Vstage[vc * 136 + toff];
            int col = vs + vc;
            int ci = col & 1023;
            int h2 = ci >> 6, d2 = ci & 63;
            *(bf16x8*)(Vt + ((size_t)(bb * 16 + h2) * 64 + d2) * 2048 + tbase + toff) = v;
        }
    }
}

// ---------------------------------------------------------------------------
// Kernel 2: attn_v17 — two q-tiles per warp over one staged KV tile.
// Block = 4 warps x 32 rows (128-row group); warp owns rows wid*16 (A) and
// 64+wid*16 (B) -> two independent softmax chains share kf/vf ds_reads and
// stage/barrier costs (2x amortization + dual-chain ILP). Grid 512 = 2/CU;
// dispatch grps {15..8} then {0..7} -> complementary CU pairs (34 tiles).
// A skips the last tile; maskedA = t==NT-2, maskedB = t==NT-1.
// ---------------------------------------------------------------------------
__global__ __launch_bounds__(256) void attn_v17(
    const short* __restrict__ Qw, const short* __restrict__ Kw,
    const short* __restrict__ Vt, short* __restrict__ Aout)
{
    __shared__ short Klds[2][64 * 64];
    __shared__ short Vlds[2][64 * 64];
    const int tid  = threadIdx.x;
    const int lane = tid & 63;
    const int wid  = tid >> 6;            // warp 0..3
    const int g = lane >> 4, cc = lane & 15;
    const int bid = blockIdx.x;
    const int bh = bid & 31;              // XCD = bh % 8
    const int gq = bid >> 5;              // 0..15
    const int grp = (gq < 8) ? (15 - gq) : (gq - 8);   // complementary pairing
    const int b = bh >> 4, h = bh & 15;
    const short* Qb = Qw + (size_t)bh * 2048 * 64;
    const short* Kb = Kw + (size_t)bh * 2048 * 64;
    const short* Vb = Vt + (size_t)bh * 64 * 2048;

    const f32x4 z4 = {0.f, 0.f, 0.f, 0.f};
    bf16x8 ones;
    #pragma unroll
    for (int i = 0; i < 8; i++) ones[i] = (short)0x3F80;   // bf16 1.0

    auto STAGE = [&](int t, int buf) {
        const int kv0 = t * 64;
        #pragma unroll
        for (int j = 0; j < 2; j++) {
            int c = tid + j * 256;        // 0..511
            int row = c >> 3, sch = (c & 7) ^ (row & 7);
            GLOAD_LDS16(Kb + (size_t)(kv0 + row) * 64 + sch * 8, &Klds[buf][c * 8]);
            GLOAD_LDS16(Vb + (size_t)row * 2048 + kv0 + sch * 8, &Vlds[buf][c * 8]);
        }
    };

    const int q0A = grp * 128 + wid * 16;        // chain A rows
    const int q0B = grp * 128 + 64 + wid * 16;   // chain B rows
    const int NT = 2 * grp + 2;

    bf16x8 qfA[2], qfB[2];
    #pragma unroll
    for (int ds = 0; ds < 2; ds++) {
        qfA[ds] = *(const bf16x8*)(Qb + (q0A + cc) * 64 + ds * 32 + g * 8);
        qfB[ds] = *(const bf16x8*)(Qb + (q0B + cc) * 64 + ds * 32 + g * 8);
    }

    f32x4 oA[4], oB[4], olA, olB;
    #pragma unroll
    for (int ch = 0; ch < 4; ch++) { oA[ch] = z4; oB[ch] = z4; }
    olA = z4; olB = z4;
    float mA = -1e30f, mB = -1e30f;

    STAGE(0, 0);
    STAGE(1, 1);
    asm volatile("s_waitcnt vmcnt(4)" ::: "memory");
    asm volatile("s_barrier" ::: "memory");

    for (int t = 0; t < NT; t++) {
        const int kv0 = t * 64;
        const short* Kt = Klds[t & 1];
        const short* Vt_ = Vlds[t & 1];
        const bool actA = (t < NT - 1);
        const bool mskA = (t == NT - 2);
        const bool mskB = (t == NT - 1);

        bf16x8 kf[8];
        #pragma unroll
        for (int kvc = 0; kvc < 4; kvc++) {
            int row = kvc * 16 + cc;
            #pragma unroll
            for (int ds = 0; ds < 2; ds++)
                kf[kvc * 2 + ds] = *(const bf16x8*)&Kt[row * 64 +
                                                       (((ds * 4 + g) ^ (row & 7)) * 8)];
        }
        f32x4 sA_[4], sB_[4];
        #pragma unroll
        for (int kvc = 0; kvc < 4; kvc++) {
            sB_[kvc] = z4;
            #pragma unroll
            for (int ds = 0; ds < 2; ds++)
                sB_[kvc] = __builtin_amdgcn_mfma_f32_16x16x32_bf16(
                    kf[kvc * 2 + ds], qfB[ds], sB_[kvc], 0, 0, 0);
        }
        if (actA) {
            #pragma unroll
            for (int kvc = 0; kvc < 4; kvc++) {
                sA_[kvc] = z4;
                #pragma unroll
                for (int ds = 0; ds < 2; ds++)
                    sA_[kvc] = __builtin_amdgcn_mfma_f32_16x16x32_bf16(
                        kf[kvc * 2 + ds], qfA[ds], sA_[kvc], 0, 0, 0);
            }
        }
        bf16x8 vf[8];
        #pragma unroll
        for (int kvh = 0; kvh < 2; kvh++)
            #pragma unroll
            for (int ch = 0; ch < 4; ch++) {
                int row = ch * 16 + cc;
                vf[kvh * 4 + ch] = *(const bf16x8*)&Vt_[row * 64 +
                                                        (((kvh * 4 + g) ^ (row & 7)) * 8)];
            }

        // ---- softmax chain B ----
        bf16x8 pbB[2];
        {
            float sv[16];
            #pragma unroll
            for (int kvc = 0; kvc < 4; kvc++)
                #pragma unroll
                for (int r = 0; r < 4; r++) {
                    float v = sB_[kvc][r];
                    if (mskB) {
                        int kv = kv0 + kvc * 16 + g * 4 + r;
                        v = (kv <= q0B + cc) ? v : -1e30f;
                    }
                    sv[kvc * 4 + r] = v;
                }
            float lm = sv[0];
            #pragma unroll
            for (int i = 1; i < 16; i++) lm = fmaxf(lm, sv[i]);
            if (__any(lm > mB + 6.0f)) {
                float mx = fmaxf(lm, __shfl_xor(lm, 16));
                mx = fmaxf(mx, __shfl_xor(mx, 32));
                float mn = fmaxf(mB, mx);
                float a = exp2f(mB - mn);
                #pragma unroll
                for (int ch = 0; ch < 4; ch++)
                    #pragma unroll
                    for (int r = 0; r < 4; r++) oB[ch][r] *= a;
                #pragma unroll
                for (int r = 0; r < 4; r++) olB[r] *= a;
                mB = mn;
            }
            #pragma unroll
            for (int i = 0; i < 16; i++) {
                float p = exp2f(sv[i] - mB);
                pbB[i >> 3][i & 7] = f2bs_trunc(p);
            }
        }
        // ---- softmax chain A ----
        bf16x8 pbA[2];
        if (actA) {
            float sv[16];
            #pragma unroll
            for (int kvc = 0; kvc < 4; kvc++)
                #pragma unroll
                for (int r = 0; r < 4; r++) {
                    float v = sA_[kvc][r];
                    if (mskA) {
                        int kv = kv0 + kvc * 16 + g * 4 + r;
                        v = (kv <= q0A + cc) ? v : -1e30f;
                    }
                    sv[kvc * 4 + r] = v;
                }
            float lm = sv[0];
            #pragma unroll
            for (int i = 1; i < 16; i++) lm = fmaxf(lm, sv[i]);
            if (__any(lm > mA + 6.0f)) {
                float mx = fmaxf(lm, __shfl_xor(lm, 16));
                mx = fmaxf(mx, __shfl_xor(mx, 32));
                float mn = fmaxf(mA, mx);
                float a = exp2f(mA - mn);
                #pragma unroll
                for (int ch = 0; ch < 4; ch++)
                    #pragma unroll
                    for (int r = 0; r < 4; r++) oA[ch][r] *= a;
                #pragma unroll
                for (int r = 0; r < 4; r++) olA[r] *= a;
                mA = mn;
            }
            #pragma unroll
            for (int i = 0; i < 16; i++) {
                float p = exp2f(sv[i] - mA);
                pbA[i >> 3][i & 7] = f2bs_trunc(p);
            }
        }

        // ---- PV both chains ----
        #pragma unroll
        for (int kvh = 0; kvh < 2; kvh++) {
            #pragma unroll
            for (int ch = 0; ch < 4; ch++)
                oB[ch] = __builtin_amdgcn_mfma_f32_16x16x32_bf16(
                    vf[kvh * 4 + ch], pbB[kvh], oB[ch], 0, 0, 0);
            olB = __builtin_amdgcn_mfma_f32_16x16x32_bf16(ones, pbB[kvh], olB, 0, 0, 0);
        }
        if (actA) {
            #pragma unroll
            for (int kvh = 0; kvh < 2; kvh++) {
                #pragma unroll
                for (int ch = 0; ch < 4; ch++)
                    oA[ch] = __builtin_amdgcn_mfma_f32_16x16x32_bf16(
                        vf[kvh * 4 + ch], pbA[kvh], oA[ch], 0, 0, 0);
                olA = __builtin_amdgcn_mfma_f32_16x16x32_bf16(ones, pbA[kvh], olA, 0, 0, 0);
            }
        }

        asm volatile("s_barrier" ::: "memory");
        if (t + 2 < NT) {
            STAGE(t + 2, t & 1);
            asm volatile("s_waitcnt vmcnt(4)" ::: "memory");
            asm volatile("s_barrier" ::: "memory");
        } else if (t + 1 < NT) {
            asm volatile("s_waitcnt vmcnt(0)" ::: "memory");
            asm volatile("s_barrier" ::: "memory");
        }
    }

    // epilogue: chain A
    {
        const float rl = 1.0f / olA[0];
        const int t2 = q0A + cc;
        #pragma unroll
        for (int ch = 0; ch < 4; ch++) {
            bf16x4 ov;
            #pragma unroll
            for (int r = 0; r < 4; r++) ov[r] = f2bs(oA[ch][r] * rl);
            *(bf16x4*)(Aout + ((size_t)b * 2048 + t2) * 1024 + h * 64 + ch * 16 + g * 4) = ov;
        }
    }
    // epilogue: chain B
    {
        const float rl = 1.0f / olB[0];
        const int t2 = q0B + cc;
        #pragma unroll
        for (int ch = 0; ch < 4; ch++) {
            bf16x4 ov;
            #pragma unroll
            for (int r = 0; r < 4; r++) ov[r] = f2bs(oB[ch][r] * rl);
            *(bf16x4*)(Aout + ((size_t)b * 2048 + t2) * 1024 + h * 64 + ch * 16 + g * 4) = ov;
        }
    }
}

// ---------------------------------------------------------------------------
// Kernel 3: projection, 8-wave counted-vmcnt structure.
// ---------------------------------------------------------------------------
__global__ __launch_bounds__(512) void proj_gemm(
    const short* __restrict__ A, const short* __restrict__ Wt,
    const float* __restrict__ bias, float* __restrict__ Out)
{
    __shared__ short Alds[2][256 * 64];
    __shared__ short Blds[2][64 * 64];
    const int tid  = threadIdx.x;
    const int lane = tid & 63;
    const int wid  = tid >> 6;
    const int wm = wid >> 1, wn = wid & 1;
    const int g = lane >> 4, cc = lane & 15;
    const int sw = cc & 7;

    const int bid  = blockIdx.x;
    const int wgid = (bid & 7) * 32 + (bid >> 3);
    const int n0 = (wgid >> 4) * 64;
    const int m0 = (wgid & 15) * 256;

    f32x4 acc[4][2];
    const f32x4 z4 = {0.f, 0.f, 0.f, 0.f};
    #pragma unroll
    for (int i = 0; i < 4; i++)
        #pragma unroll
        for (int j = 0; j < 2; j++) acc[i][j] = z4;

    auto STAGE = [&](int t, int buf) {
        const int k0 = t * 64;
        #pragma unroll
        for (int j = 0; j < 4; j++) {
            int c = j * 512 + wid * 64 + lane;
            int row = c >> 3, sch = (c & 7) ^ (row & 7);
            GLOAD_LDS16(A + (size_t)(m0 + row) * 1024 + k0 + sch * 8,
                        &Alds[buf][c * 8]);
        }
        {
            int c = wid * 64 + lane;
            int row = c >> 3, sch = (c & 7) ^ (row & 7);
            GLOAD_LDS16(Wt + (size_t)(n0 + row) * 1024 + k0 + sch * 8,
                        &Blds[buf][c * 8]);
        }
    };

    STAGE(0, 0);
    STAGE(1, 1);
    asm volatile("s_waitcnt vmcnt(5)" ::: "memory");
    asm volatile("s_barrier" ::: "memory");

    const int NT = 16;
    for (int t = 0; t < NT; t++) {
        const short* Ab = Alds[t & 1];
        const short* Bb = Blds[t & 1];

        bf16x8 bfr[2][2];
        #pragma unroll
        for (int nf = 0; nf < 2; nf++)
            #pragma unroll
            for (int kk = 0; kk < 2; kk++)
                bfr[nf][kk] = *(const bf16x8*)&Bb[(wn * 32 + nf * 16 + cc) * 64 +
                                                  ((kk * 4 + g) ^ sw) * 8];
        bf16x8 af[4][2];
        #pragma unroll
        for (int mf = 0; mf < 4; mf++)
            #pragma unroll
            for (int kk = 0; kk < 2; kk++)
                af[mf][kk] = *(const bf16x8*)&Ab[(wm * 64 + mf * 16 + cc) * 64 +
                                                 ((kk * 4 + g) ^ sw) * 8];
        __builtin_amdgcn_s_setprio(1);
        #pragma unroll
        for (int mf = 0; mf < 4; mf++)
            #pragma unroll
            for (int nf = 0; nf < 2; nf++)
                #pragma unroll
                for (int kk = 0; kk < 2; kk++)
                    acc[mf][nf] = __builtin_amdgcn_mfma_f32_16x16x32_bf16(
                        af[mf][kk], bfr[nf][kk], acc[mf][nf], 0, 0, 0);
        __builtin_amdgcn_s_setprio(0);

        asm volatile("s_barrier" ::: "memory");
        if (t + 2 < NT) {
            STAGE(t + 2, t & 1);
            asm volatile("s_waitcnt vmcnt(5)" ::: "memory");
            asm volatile("s_barrier" ::: "memory");
        } else if (t + 1 < NT) {
            asm volatile("s_waitcnt vmcnt(0)" ::: "memory");
            asm volatile("s_barrier" ::: "memory");
        }
    }

    #pragma unroll
    for (int nf = 0; nf < 2; nf++) {
        int col = n0 + wn * 32 + nf * 16 + cc;
        float bv = bias[col];
        #pragma unroll
        for (int mf = 0; mf < 4; mf++) {
            #pragma unroll
            for (int r = 0; r < 4; r++) {
                int row = m0 + wm * 64 + mf * 16 + g * 4 + r;
                Out[(size_t)row * 1024 + col] = acc[mf][nf][r] + bv;
            }
        }
    }
}

// ---------------------------------------------------------------------------
extern "C" void kernel_launch(void* const* d_in, const int* in_sizes, int n_in,
                              void* d_out, int out_size, void* d_ws, size_t ws_size,
                              hipStream_t stream)
{
    const float* x      = (const float*)d_in[0];
    const float* W_attn = (const float*)d_in[1];
    const float* b_attn = (const float*)d_in[2];
    const float* W_proj = (const float*)d_in[3];
    const float* b_proj = (const float*)d_in[4];
    float* out = (float*)d_out;

    const size_t SZ = (size_t)4096 * 1024;
    short* R1 = (short*)d_ws;                  // Wt_attn, later Aout
    short* Qw = R1 + SZ;                       // later Wt_proj
    short* Kw = Qw + SZ;
    short* Vt = Kw + SZ;

    short* Wt_attn = R1;
    short* Aout    = R1;
    short* Wt_proj = Qw;
    short* Xb      = (short*)d_out;            // d_out as bf16 scratch until proj

    convx<<<dim3(2048), 256, 0, stream>>>(x, Xb);
    convt<<<dim3(48, 16), 256, 0, stream>>>(W_attn, Wt_attn, 1024, 3072);
    qkv_gemm<<<dim3(512), 512, 0, stream>>>(Xb, Wt_attn, b_attn, Qw, Kw, Vt);
    attn_v17<<<dim3(512), 256, 0, stream>>>(Qw, Kw, Vt, Aout);
    convt<<<dim3(16, 16), 256, 0, stream>>>(W_proj, Wt_proj, 1024, 1024);
    proj_gemm<<<dim3(256), 512, 0, stream>>>(Aout, Wt_proj, b_proj, out);
}

// Round 25
// 105.578 us; speedup vs baseline: 1.1621x; 1.1621x over previous
//
#include <hip/hip_runtime.h>
#include <hip/hip_bf16.h>

// B=2, T=2048, C=1024, H=16, D=64
// convx -> convt(W_attn) -> qkv_gemm (128x192, 2 blocks/CU, 8mx8n XCD chunks)
// -> attn_v16 (4-domain, l-on-MFMA) -> convt -> proj_gemm
// [round-23 best configuration, reverted after v17 regression]

typedef __attribute__((ext_vector_type(8))) short bf16x8;
typedef __attribute__((ext_vector_type(4))) short bf16x4;
typedef __attribute__((ext_vector_type(4))) float f32x4;

__device__ __forceinline__ short f2bs(float f) {
    union { __hip_bfloat16 h; short s; } u;
    u.h = __float2bfloat16(f);
    return u.s;
}

__device__ __forceinline__ short f2bs_trunc(float f) {
    return (short)(__float_as_uint(f) >> 16);
}

#define GLOAD_LDS16(gp, lp)                                                        \
    __builtin_amdgcn_global_load_lds((const __attribute__((address_space(1))) void*)(gp), \
                                     (__attribute__((address_space(3))) void*)(lp), 16, 0, 0)

// ---------------------------------------------------------------------------
__global__ __launch_bounds__(256) void convx(
    const float* __restrict__ X, short* __restrict__ Xb)
{
    const size_t i = ((size_t)blockIdx.x * 256 + threadIdx.x) * 8;
    float4 a = *(const float4*)(X + i);
    float4 b = *(const float4*)(X + i + 4);
    bf16x8 s;
    s[0] = f2bs(a.x); s[1] = f2bs(a.y); s[2] = f2bs(a.z); s[3] = f2bs(a.w);
    s[4] = f2bs(b.x); s[5] = f2bs(b.y); s[6] = f2bs(b.z); s[7] = f2bs(b.w);
    *(bf16x8*)(Xb + i) = s;
}

// ---------------------------------------------------------------------------
__global__ __launch_bounds__(256) void convt(
    const float* __restrict__ W, short* __restrict__ Wt, int K, int N)
{
    __shared__ short t[64 * 72];
    const int tid = threadIdx.x;
    const int n0 = blockIdx.x * 64, k0 = blockIdx.y * 64;
    #pragma unroll
    for (int i = 0; i < 4; i++) {
        int k = (tid >> 4) + i * 16;
        int n = (tid & 15) * 4;
        float4 v = *(const float4*)(W + (size_t)(k0 + k) * N + n0 + n);
        t[(n + 0) * 72 + k] = f2bs(v.x);
        t[(n + 1) * 72 + k] = f2bs(v.y);
        t[(n + 2) * 72 + k] = f2bs(v.z);
        t[(n + 3) * 72 + k] = f2bs(v.w);
    }
    __syncthreads();
    #pragma unroll
    for (int i = 0; i < 2; i++) {
        int n  = (tid >> 3) + i * 32;
        int kc = (tid & 7) * 8;
        bf16x8 v = *(const bf16x8*)&t[n * 72 + kc];
        *(bf16x8*)(Wt + (size_t)(n0 + n) * K + k0 + kc) = v;
    }
}

// ---------------------------------------------------------------------------
// Kernel 1: QKV GEMM, 128x192 tile, BK=64, 8 waves, 2 blocks/CU, vmcnt(5),
// 8m x 8n XCD chunks. V via LDS-transpose epilogue.
// ---------------------------------------------------------------------------
__global__ __launch_bounds__(512) void qkv_gemm(
    const short* __restrict__ Xb, const short* __restrict__ Wt,
    const float* __restrict__ bias,
    short* __restrict__ Qw, short* __restrict__ Kw, short* __restrict__ Vt)
{
    __shared__ short LB[40960];           // A dbuf 2x8192, B dbuf 2x12288

    const int tid  = threadIdx.x;
    const int lane = tid & 63;
    const int wid  = tid >> 6;
    const int wm = wid >> 2, wn = wid & 3;
    const int g = lane >> 4, cc = lane & 15;
    const int sw = cc & 7;

    const int bid   = blockIdx.x;
    const int xcd   = bid & 7;
    const int r     = bid >> 3;
    const int m0 = ((xcd & 3) * 8 + (r & 7)) * 128;
    const int n0 = ((xcd >> 2) * 8 + (r >> 3)) * 192;

    f32x4 acc[4][3];
    const f32x4 z4 = {0.f, 0.f, 0.f, 0.f};
    #pragma unroll
    for (int i = 0; i < 4; i++)
        #pragma unroll
        for (int j = 0; j < 3; j++) acc[i][j] = z4;

    auto STAGE = [&](int t, int buf) {
        const int k0 = t * 64;
        short* Ab = LB + buf * 8192;
        short* Bb = LB + 16384 + buf * 12288;
        #pragma unroll
        for (int j = 0; j < 2; j++) {
            int c = j * 512 + tid;
            int row = c >> 3, sch = (c & 7) ^ (row & 7);
            GLOAD_LDS16(Xb + (size_t)(m0 + row) * 1024 + k0 + sch * 8, Ab + c * 8);
        }
        #pragma unroll
        for (int j = 0; j < 3; j++) {
            int c = j * 512 + tid;
            int row = c >> 3, sch = (c & 7) ^ (row & 7);
            GLOAD_LDS16(Wt + (size_t)(n0 + row) * 1024 + k0 + sch * 8, Bb + c * 8);
        }
    };

    STAGE(0, 0);
    STAGE(1, 1);
    asm volatile("s_waitcnt vmcnt(5)" ::: "memory");
    asm volatile("s_barrier" ::: "memory");

    const int NT = 16;
    for (int t = 0; t < NT; t++) {
        const short* Ab = LB + (t & 1) * 8192;
        const short* Bb = LB + 16384 + (t & 1) * 12288;

        bf16x8 bfr[3][2];
        #pragma unroll
        for (int nf = 0; nf < 3; nf++)
            #pragma unroll
            for (int kk = 0; kk < 2; kk++)
                bfr[nf][kk] = *(const bf16x8*)&Bb[(wn * 48 + nf * 16 + cc) * 64 +
                                                  ((kk * 4 + g) ^ sw) * 8];
        bf16x8 af[4][2];
        #pragma unroll
        for (int mf = 0; mf < 4; mf++)
            #pragma unroll
            for (int kk = 0; kk < 2; kk++)
                af[mf][kk] = *(const bf16x8*)&Ab[(wm * 64 + mf * 16 + cc) * 64 +
                                                 ((kk * 4 + g) ^ sw) * 8];
        __builtin_amdgcn_s_setprio(1);
        #pragma unroll
        for (int mf = 0; mf < 4; mf++)
            #pragma unroll
            for (int nf = 0; nf < 3; nf++)
                #pragma unroll
                for (int kk = 0; kk < 2; kk++)
                    acc[mf][nf] = __builtin_amdgcn_mfma_f32_16x16x32_bf16(
                        af[mf][kk], bfr[nf][kk], acc[mf][nf], 0, 0, 0);
        __builtin_amdgcn_s_setprio(0);

        asm volatile("s_barrier" ::: "memory");
        if (t + 2 < NT) {
            STAGE(t + 2, t & 1);
            asm volatile("s_waitcnt vmcnt(5)" ::: "memory");
            asm volatile("s_barrier" ::: "memory");
        } else if (t + 1 < NT) {
            asm volatile("s_waitcnt vmcnt(0)" ::: "memory");
            asm volatile("s_barrier" ::: "memory");
        }
    }

    // ---- epilogue ----
    const float QSCALE = 0.04508422976f;
    const int vs = (n0 > 2048) ? n0 : 2048;
    const int nV = n0 + 192 - vs;
    short* Vstage = LB;                              // overlay [vcol][136]

    __syncthreads();

    #pragma unroll
    for (int nf = 0; nf < 3; nf++) {
        int col = n0 + wn * 48 + nf * 16 + cc;
        int which = col >> 10;
        int ci = col & 1023;
        int h = ci >> 6, d = ci & 63;
        float bv = bias[col];
        #pragma unroll
        for (int mf = 0; mf < 4; mf++) {
            if (which == 2) {
                int tl = wm * 64 + mf * 16 + g * 4;
                int pl = (tl & ~31) | (((tl >> 2) & 3) * 8 + ((tl >> 4) & 1) * 4);
                bf16x4 pk;
                #pragma unroll
                for (int r2 = 0; r2 < 4; r2++) pk[r2] = f2bs(acc[mf][nf][r2] + bv);
                *(bf16x4*)&Vstage[(col - vs) * 136 + pl] = pk;
            } else {
                #pragma unroll
                for (int r2 = 0; r2 < 4; r2++) {
                    int row = m0 + wm * 64 + mf * 16 + g * 4 + r2;
                    int b = row >> 11, tt = row & 2047;
                    int bh = b * 16 + h;
                    float v = acc[mf][nf][r2] + bv;
                    if (which == 0) Qw[((size_t)bh * 2048 + tt) * 64 + d] = f2bs(v * QSCALE);
                    else            Kw[((size_t)bh * 2048 + tt) * 64 + d] = f2bs(v);
                }
            }
        }
    }

    if (nV > 0) {
        __syncthreads();
        const int bb = m0 >> 11;
        const int tbase = m0 & 2047;
        const int total = nV * 16;
        for (int cidx = tid; cidx < total; cidx += 512) {
            int vc = cidx >> 4, toff = (cidx & 15) * 8;
            bf16x8 v = *(const bf16x8*)&Vstage[vc * 136 + toff];
            int col = vs + vc;
            int ci = col & 1023;
            int h2 = ci >> 6, d2 = ci & 63;
            *(bf16x8*)(Vt + ((size_t)(bb * 16 + h2) * 64 + d2) * 2048 + tbase + toff) = v;
        }
    }
}

// ---------------------------------------------------------------------------
// Kernel 2: attn_v16 — 256-thr block = 4 warps x 16 rows (64-row group),
// one group per block, grid 1024 = 4 blocks/CU, longest-first. Softmax
// denominator accumulated on the MFMA pipe via ones-fragment.
// ---------------------------------------------------------------------------
__global__ __launch_bounds__(256) void attn_v16(
    const short* __restrict__ Qw, const short* __restrict__ Kw,
    const short* __restrict__ Vt, short* __restrict__ Aout)
{
    __shared__ short Klds[2][64 * 64];
    __shared__ short Vlds[2][64 * 64];
    const int tid  = threadIdx.x;
    const int lane = tid & 63;
    const int wid  = tid >> 6;            // warp 0..3
    const int g = lane >> 4, cc = lane & 15;
    const int bid = blockIdx.x;
    const int bh = bid & 31;              // XCD = bh % 8
    const int grp = 31 - (bid >> 5);      // 0..31, longest first
    const int b = bh >> 4, h = bh & 15;
    const short* Qb = Qw + (size_t)bh * 2048 * 64;
    const short* Kb = Kw + (size_t)bh * 2048 * 64;
    const short* Vb = Vt + (size_t)bh * 64 * 2048;

    const f32x4 z4 = {0.f, 0.f, 0.f, 0.f};
    bf16x8 ones;
    #pragma unroll
    for (int i = 0; i < 8; i++) ones[i] = (short)0x3F80;   // bf16 1.0

    auto STAGE = [&](int t, int buf) {
        const int kv0 = t * 64;
        #pragma unroll
        for (int j = 0; j < 2; j++) {
            int c = tid + j * 256;        // 0..511
            int row = c >> 3, sch = (c & 7) ^ (row & 7);
            GLOAD_LDS16(Kb + (size_t)(kv0 + row) * 64 + sch * 8, &Klds[buf][c * 8]);
            GLOAD_LDS16(Vb + (size_t)row * 2048 + kv0 + sch * 8, &Vlds[buf][c * 8]);
        }
    };

    const int q0 = grp * 64 + wid * 16;   // this warp's 16 q-rows
    const int NT = grp + 1;

    bf16x8 qf0[2];
    #pragma unroll
    for (int ds = 0; ds < 2; ds++)
        qf0[ds] = *(const bf16x8*)(Qb + (q0 + cc) * 64 + ds * 32 + g * 8);

    f32x4 o[4], ol;
    #pragma unroll
    for (int ch = 0; ch < 4; ch++) o[ch] = z4;
    ol = z4;
    float m_r = -1e30f;

    STAGE(0, 0);
    STAGE((NT > 1) ? 1 : 0, 1);           // dummy restage if NT==1
    asm volatile("s_waitcnt vmcnt(4)" ::: "memory");
    asm volatile("s_barrier" ::: "memory");

    for (int t = 0; t < NT; t++) {
        const int kv0 = t * 64;
        const short* Kt = Klds[t & 1];
        const short* Vt_ = Vlds[t & 1];
        const bool masked = (t == NT - 1);

        bf16x8 kf[8];
        #pragma unroll
        for (int kvc = 0; kvc < 4; kvc++) {
            int row = kvc * 16 + cc;
            #pragma unroll
            for (int ds = 0; ds < 2; ds++)
                kf[kvc * 2 + ds] = *(const bf16x8*)&Kt[row * 64 +
                                                       (((ds * 4 + g) ^ (row & 7)) * 8)];
        }
        f32x4 s_[4];
        #pragma unroll
        for (int kvc = 0; kvc < 4; kvc++) {
            s_[kvc] = z4;
            #pragma unroll
            for (int ds = 0; ds < 2; ds++)
                s_[kvc] = __builtin_amdgcn_mfma_f32_16x16x32_bf16(
                    kf[kvc * 2 + ds], qf0[ds], s_[kvc], 0, 0, 0);
        }
        bf16x8 vf[8];
        #pragma unroll
        for (int kvh = 0; kvh < 2; kvh++)
            #pragma unroll
            for (int ch = 0; ch < 4; ch++) {
                int row = ch * 16 + cc;
                vf[kvh * 4 + ch] = *(const bf16x8*)&Vt_[row * 64 +
                                                        (((kvh * 4 + g) ^ (row & 7)) * 8)];
            }

        bf16x8 pb_[2];
        {
            float sv[16];
            #pragma unroll
            for (int kvc = 0; kvc < 4; kvc++)
                #pragma unroll
                for (int r = 0; r < 4; r++) {
                    float v = s_[kvc][r];
                    if (masked) {
                        int kv = kv0 + kvc * 16 + g * 4 + r;
                        v = (kv <= q0 + cc) ? v : -1e30f;
                    }
                    sv[kvc * 4 + r] = v;
                }
            float lm = sv[0];
            #pragma unroll
            for (int i = 1; i < 16; i++) lm = fmaxf(lm, sv[i]);
            if (__any(lm > m_r + 6.0f)) {
                float mx = fmaxf(lm, __shfl_xor(lm, 16));
                mx = fmaxf(mx, __shfl_xor(mx, 32));
                float mn = fmaxf(m_r, mx);
                float a = exp2f(m_r - mn);
                #pragma unroll
                for (int ch = 0; ch < 4; ch++)
                    #pragma unroll
                    for (int r = 0; r < 4; r++) o[ch][r] *= a;
                #pragma unroll
                for (int r = 0; r < 4; r++) ol[r] *= a;
                m_r = mn;
            }
            #pragma unroll
            for (int i = 0; i < 16; i++) {
                float p = exp2f(sv[i] - m_r);
                pb_[i >> 3][i & 7] = f2bs_trunc(p);
            }
        }
        #pragma unroll
        for (int kvh = 0; kvh < 2; kvh++) {
            #pragma unroll
            for (int ch = 0; ch < 4; ch++)
                o[ch] = __builtin_amdgcn_mfma_f32_16x16x32_bf16(
                    vf[kvh * 4 + ch], pb_[kvh], o[ch], 0, 0, 0);
            ol = __builtin_amdgcn_mfma_f32_16x16x32_bf16(ones, pb_[kvh], ol, 0, 0, 0);
        }

        asm volatile("s_barrier" ::: "memory");
        if (t + 2 < NT) {
            STAGE(t + 2, t & 1);
            asm volatile("s_waitcnt vmcnt(4)" ::: "memory");
            asm volatile("s_barrier" ::: "memory");
        } else if (t + 1 < NT) {
            asm volatile("s_waitcnt vmcnt(0)" ::: "memory");
            asm volatile("s_barrier" ::: "memory");
        }
    }

    const float rl = 1.0f / ol[0];        // l(q=cc), replicated across rows
    const int t2 = q0 + cc;
    #pragma unroll
    for (int ch = 0; ch < 4; ch++) {
        bf16x4 ov;
        #pragma unroll
        for (int r = 0; r < 4; r++) ov[r] = f2bs(o[ch][r] * rl);
        *(bf16x4*)(Aout + ((size_t)b * 2048 + t2) * 1024 + h * 64 + ch * 16 + g * 4) = ov;
    }
}

// ---------------------------------------------------------------------------
// Kernel 3: projection, 8-wave counted-vmcnt structure.
// ---------------------------------------------------------------------------
__global__ __launch_bounds__(512) void proj_gemm(
    const short* __restrict__ A, const short* __restrict__ Wt,
    const float* __restrict__ bias, float* __restrict__ Out)
{
    __shared__ short Alds[2][256 * 64];
    __shared__ short Blds[2][64 * 64];
    const int tid  = threadIdx.x;
    const int lane = tid & 63;
    const int wid  = tid >> 6;
    const int wm = wid >> 1, wn = wid & 1;
    const int g = lane >> 4, cc = lane & 15;
    const int sw = cc & 7;

    const int bid  = blockIdx.x;
    const int wgid = (bid & 7) * 32 + (bid >> 3);
    const int n0 = (wgid >> 4) * 64;
    const int m0 = (wgid & 15) * 256;

    f32x4 acc[4][2];
    const f32x4 z4 = {0.f, 0.f, 0.f, 0.f};
    #pragma unroll
    for (int i = 0; i < 4; i++)
        #pragma unroll
        for (int j = 0; j < 2; j++) acc[i][j] = z4;

    auto STAGE = [&](int t, int buf) {
        const int k0 = t * 64;
        #pragma unroll
        for (int j = 0; j < 4; j++) {
            int c = j * 512 + wid * 64 + lane;
            int row = c >> 3, sch = (c & 7) ^ (row & 7);
            GLOAD_LDS16(A + (size_t)(m0 + row) * 1024 + k0 + sch * 8,
                        &Alds[buf][c * 8]);
        }
        {
            int c = wid * 64 + lane;
            int row = c >> 3, sch = (c & 7) ^ (row & 7);
            GLOAD_LDS16(Wt + (size_t)(n0 + row) * 1024 + k0 + sch * 8,
                        &Blds[buf][c * 8]);
        }
    };

    STAGE(0, 0);
    STAGE(1, 1);
    asm volatile("s_waitcnt vmcnt(5)" ::: "memory");
    asm volatile("s_barrier" ::: "memory");

    const int NT = 16;
    for (int t = 0; t < NT; t++) {
        const short* Ab = Alds[t & 1];
        const short* Bb = Blds[t & 1];

        bf16x8 bfr[2][2];
        #pragma unroll
        for (int nf = 0; nf < 2; nf++)
            #pragma unroll
            for (int kk = 0; kk < 2; kk++)
                bfr[nf][kk] = *(const bf16x8*)&Bb[(wn * 32 + nf * 16 + cc) * 64 +
                                                  ((kk * 4 + g) ^ sw) * 8];
        bf16x8 af[4][2];
        #pragma unroll
        for (int mf = 0; mf < 4; mf++)
            #pragma unroll
            for (int kk = 0; kk < 2; kk++)
                af[mf][kk] = *(const bf16x8*)&Ab[(wm * 64 + mf * 16 + cc) * 64 +
                                                 ((kk * 4 + g) ^ sw) * 8];
        __builtin_amdgcn_s_setprio(1);
        #pragma unroll
        for (int mf = 0; mf < 4; mf++)
            #pragma unroll
            for (int nf = 0; nf < 2; nf++)
                #pragma unroll
                for (int kk = 0; kk < 2; kk++)
                    acc[mf][nf] = __builtin_amdgcn_mfma_f32_16x16x32_bf16(
                        af[mf][kk], bfr[nf][kk], acc[mf][nf], 0, 0, 0);
        __builtin_amdgcn_s_setprio(0);

        asm volatile("s_barrier" ::: "memory");
        if (t + 2 < NT) {
            STAGE(t + 2, t & 1);
            asm volatile("s_waitcnt vmcnt(5)" ::: "memory");
            asm volatile("s_barrier" ::: "memory");
        } else if (t + 1 < NT) {
            asm volatile("s_waitcnt vmcnt(0)" ::: "memory");
            asm volatile("s_barrier" ::: "memory");
        }
    }

    #pragma unroll
    for (int nf = 0; nf < 2; nf++) {
        int col = n0 + wn * 32 + nf * 16 + cc;
        float bv = bias[col];
        #pragma unroll
        for (int mf = 0; mf < 4; mf++) {
            #pragma unroll
            for (int r = 0; r < 4; r++) {
                int row = m0 + wm * 64 + mf * 16 + g * 4 + r;
                Out[(size_t)row * 1024 + col] = acc[mf][nf][r] + bv;
            }
        }
    }
}

// ---------------------------------------------------------------------------
extern "C" void kernel_launch(void* const* d_in, const int* in_sizes, int n_in,
                              void* d_out, int out_size, void* d_ws, size_t ws_size,
                              hipStream_t stream)
{
    const float* x      = (const float*)d_in[0];
    const float* W_attn = (const float*)d_in[1];
    const float* b_attn = (const float*)d_in[2];
    const float* W_proj = (const float*)d_in[3];
    const float* b_proj = (const float*)d_in[4];
    float* out = (float*)d_out;

    const size_t SZ = (size_t)4096 * 1024;
    short* R1 = (short*)d_ws;                  // Wt_attn, later Aout
    short* Qw = R1 + SZ;                       // later Wt_proj
    short* Kw = Qw + SZ;
    short* Vt = Kw + SZ;

    short* Wt_attn = R1;
    short* Aout    = R1;
    short* Wt_proj = Qw;
    short* Xb      = (short*)d_out;            // d_out as bf16 scratch until proj

    convx<<<dim3(2048), 256, 0, stream>>>(x, Xb);
    convt<<<dim3(48, 16), 256, 0, stream>>>(W_attn, Wt_attn, 1024, 3072);
    qkv_gemm<<<dim3(512), 512, 0, stream>>>(Xb, Wt_attn, b_attn, Qw, Kw, Vt);
    attn_v16<<<dim3(1024), 256, 0, stream>>>(Qw, Kw, Vt, Aout);
    convt<<<dim3(16, 16), 256, 0, stream>>>(W_proj, Wt_proj, 1024, 1024);
    proj_gemm<<<dim3(256), 512, 0, stream>>>(Aout, Wt_proj, b_proj, out);
}